// Round 3
// baseline (623.564 us; speedup 1.0000x reference)
//
#include <hip/hip_runtime.h>
#include <math.h>

#define Bq 4
#define Hq 512
#define Nq 64
#define Lq 2048
#define PARAM (Hq*Nq)   // 32768

typedef float v2f __attribute__((ext_vector_type(2)));

// ---------------------------------------------------------------------------
// Phase 1: per-(h,n) parameter prep.
// ---------------------------------------------------------------------------
__global__ void prep_kernel(const float* __restrict__ log_dt,
                            const float* __restrict__ log_A_real,
                            const float* __restrict__ A_imag,
                            const float* __restrict__ B_re, const float* __restrict__ B_im,
                            const float* __restrict__ C_re, const float* __restrict__ C_im,
                            float* __restrict__ wr_, float* __restrict__ wi_,
                            float* __restrict__ a0, float* __restrict__ b0,
                            float* __restrict__ a1, float* __restrict__ b1) {
    int idx = blockIdx.x * blockDim.x + threadIdx.x;
    if (idx >= PARAM) return;
    int h = idx >> 6;
    float dt = expf(log_dt[h]);
    float Ar = -expf(log_A_real[idx]);
    float Ai = A_imag[idx];
    float er = expf(Ar * dt);
    float wr = er * cosf(Ai * dt);
    float wi = er * sinf(Ai * dt);
    wr_[idx] = wr; wi_[idx] = wi;
    float mr = wr - 1.0f, mi = wi;
    float den = Ar * Ar + Ai * Ai;
    float qr = (mr * Ar + mi * Ai) / den;
    float qi = (mi * Ar - mr * Ai) / den;
    float Br = B_re[idx], Bi = B_im[idx];
    float dBr = Br * qr - Bi * qi;
    float dBi = Br * qi + Bi * qr;
    float cr = C_re[idx], ci = C_im[idx];
    a0[idx] =  2.0f * (cr * dBr - ci * dBi);
    b0[idx] = -2.0f * (cr * dBi + ci * dBr);
    cr = C_re[PARAM + idx]; ci = C_im[PARAM + idx];
    a1[idx] =  2.0f * (cr * dBr - ci * dBi);
    b1[idx] = -2.0f * (cr * dBi + ci * dBr);
}

// ---------------------------------------------------------------------------
// Phase 1b: Wt[k][o] = W[o][k]  (512x512) so GEMM can s_load W rows.
// ---------------------------------------------------------------------------
__global__ __launch_bounds__(256)
void transpose_kernel(const float* __restrict__ W, float* __restrict__ Wt) {
    __shared__ float t[32][33];
    int bx = blockIdx.x * 32;          // k base
    int by = blockIdx.y * 32;          // o base
    int tx = threadIdx.x & 31, ty = threadIdx.x >> 5;   // ty 0..7
    #pragma unroll
    for (int r = 0; r < 4; ++r)
        t[ty + 8 * r][tx] = W[(size_t)(by + ty + 8 * r) * Hq + bx + tx];
    __syncthreads();
    #pragma unroll
    for (int r = 0; r < 4; ++r)
        Wt[(size_t)(bx + ty + 8 * r) * Hq + by + tx] = t[tx][ty + 8 * r];
}

// ---------------------------------------------------------------------------
// Phase 2: LayerNorm over H per (b,l). Round-1 config: 512 blocks, 16l x 16h.
// ---------------------------------------------------------------------------
__global__ __launch_bounds__(256)
void ln_kernel(const float* __restrict__ x, const float* __restrict__ lnw,
               const float* __restrict__ lnb, float* __restrict__ z) {
    int blk = blockIdx.x;
    int b  = blk / (Lq / 16);
    int l0 = (blk % (Lq / 16)) * 16;
    int tx = threadIdx.x & 15;   // l within tile
    int ty = threadIdx.x >> 4;   // h group
    const float* xb = x + (size_t)b * Hq * Lq;
    float s = 0.f, s2 = 0.f;
    for (int h = ty; h < Hq; h += 16) {
        float v = xb[h * Lq + l0 + tx];
        s += v; s2 += v * v;
    }
    __shared__ float rs_[16][17], r2_[16][17], mu_s[16], sg_s[16];
    rs_[ty][tx] = s; r2_[ty][tx] = s2;
    __syncthreads();
    if (ty == 0) {
        float a = 0.f, c = 0.f;
        #pragma unroll
        for (int i = 0; i < 16; ++i) { a += rs_[i][tx]; c += r2_[i][tx]; }
        float mu = a * (1.0f / Hq);
        float var = c * (1.0f / Hq) - mu * mu;
        mu_s[tx] = mu;
        sg_s[tx] = rsqrtf(var + 1e-5f);
    }
    __syncthreads();
    float mu = mu_s[tx], rs = sg_s[tx];
    float* zb = z + (size_t)b * Hq * Lq;
    for (int h = ty; h < Hq; h += 16) {
        float v = xb[h * Lq + l0 + tx];
        zb[h * Lq + l0 + tx] = (v - mu) * rs * lnw[h] + lnb[h];
    }
}

// ---------------------------------------------------------------------------
// Phase 3: fused bidirectional SSM scan + activation epilogue.
// One wave per (b,h); lane n = state index; packed fp32 carries BOTH
// directions. 16-column transpose tiles keep LDS at ~8.8 KB (occupancy!).
// ---------------------------------------------------------------------------
__global__ __launch_bounds__(64)
void scan_kernel(const float* __restrict__ z,
                 const float* __restrict__ wr_, const float* __restrict__ wi_,
                 const float* __restrict__ a0, const float* __restrict__ b0,
                 const float* __restrict__ a1, const float* __restrict__ b1,
                 const float* __restrict__ Dv,
                 float* __restrict__ y0, float* __restrict__ y1) {
    int bh = blockIdx.x;               // 0..B*H-1
    int h = bh & (Hq - 1);
    int n = threadIdx.x;
    int pidx = h * Nq + n;
    float wr = wr_[pidx], wi = wi_[pidx];
    v2f wr2 = { wr, wr }, wi2 = { wi, wi };
    v2f pa = { a0[pidx], a1[pidx] };
    v2f pb = { b0[pidx], b1[pidx] };

    // [64][17] b32 tiles: both write (fixed k) and read (fixed tloc) patterns
    // are 2-way bank aliasing only = free (m136).
    __shared__ float tile_f[64][17];
    __shared__ float tile_b[64][17];
    __shared__ v2f zp[16];             // interleaved {z_fwd, z_bwd} per k

    const float* zz = z + (size_t)bh * Lq;
    float* y0r = y0 + (size_t)bh * Lq;
    float* y1r = y1 + (size_t)bh * Lq;

    v2f sr = {0.f, 0.f}, si = {0.f, 0.f};
    int tloc = n & 15;

    for (int q0 = 0; q0 < Lq; q0 += 16) {
        if (n < 16)                  ((float*)zp)[2 * n]            = zz[q0 + n];
        else if (n >= 32 && n < 48)  ((float*)zp)[2 * (n - 32) + 1] = zz[Lq - 1 - q0 - (n - 32)];
        __syncthreads();
        #pragma unroll
        for (int k = 0; k < 16; ++k) {
            v2f zt = zp[k];                                   // b64 broadcast
            v2f t1 = __builtin_elementwise_fma(wi2, si, -zt); // wi*si - z
            v2f t2 = wi2 * sr;
            sr = __builtin_elementwise_fma(wr2, sr, -t1);     // wr*sr-wi*si+z
            si = __builtin_elementwise_fma(wr2, si, t2);
            v2f p = __builtin_elementwise_fma(pa, sr, pb * si);
            tile_f[n][k] = p.x;
            tile_b[n][k] = p.y;
        }
        __syncthreads();
        int quad = n >> 4;
        float af = 0.f, ab = 0.f;
        #pragma unroll
        for (int j = 0; j < 16; ++j) {
            af += tile_f[quad * 16 + j][tloc];
            ab += tile_b[quad * 16 + j][tloc];
        }
        af += __shfl_xor(af, 16, 64);
        af += __shfl_xor(af, 32, 64);
        ab += __shfl_xor(ab, 16, 64);
        ab += __shfl_xor(ab, 32, 64);
        if (n < 16) {
            y0r[q0 + n] = af;
        } else if (n < 32) {
            int pos = Lq - 2 - q0 - tloc;
            if (pos >= 0) y1r[pos] = ab;     // y1[L-1] handled as 0 in tail
        }
    }
    __syncthreads();
    // ---- activation tail: u = gelu(y0 + y1 + D*z), in-place into y0 ----
    float d = Dv[h];
    for (int t = n; t < Lq; t += 64) {
        float v0 = y0r[t];
        float v1 = (t == Lq - 1) ? 0.f : y1r[t];
        float v = v0 + v1 + d * zz[t];
        float g = 0.7978845608028654f * (v + 0.044715f * v * v * v);
        g = fminf(fmaxf(g, -15.f), 15.f);
        float e = __expf(2.0f * g);
        float th = (e - 1.0f) * __builtin_amdgcn_rcpf(e + 1.0f);
        y0r[t] = 0.5f * v * (1.0f + th);
    }
}

// ---------------------------------------------------------------------------
// Phase 5: out[b,o,l] = bias[o] + x[b,o,l] + sum_k W[o,k]*u[b,k,l]
// Scalar-broadcast GEMM, zero LDS: lane = l (coalesced u loads); W read via
// wave-uniform addresses from Wt[k][o] -> s_load on the scalar pipe; per k:
// 1 global_load_dword + 32 v_fmac(acc, s_w, v_u).
// Block = 4 waves x 32 o = 128 o, 64 l. Grid (32, 4, 4) = 512 blocks.
// ---------------------------------------------------------------------------
__global__ __launch_bounds__(256)
void gemm_kernel(const float* __restrict__ u, const float* __restrict__ Wt,
                 const float* __restrict__ bias, const float* __restrict__ x,
                 float* __restrict__ out) {
    int l0 = blockIdx.x * 64;
    int o0 = blockIdx.y * 128 + (threadIdx.x >> 6) * 32;   // per-wave o base
    int b  = blockIdx.z;
    int lane = threadIdx.x & 63;
    const float* ub = u + (size_t)b * Hq * Lq + l0 + lane;

    float acc[32];
    #pragma unroll
    for (int o = 0; o < 32; ++o) acc[o] = 0.f;

    // 4-deep u prefetch ring (unguarded tail reads land in y1's ws region —
    // allocated, value unused).
    float up[4];
    #pragma unroll
    for (int i = 0; i < 4; ++i) up[i] = ub[(size_t)i * Lq];

    for (int k0 = 0; k0 < Hq; k0 += 4) {
        #pragma unroll
        for (int kk = 0; kk < 4; ++kk) {
            float uv = up[kk];
            up[kk] = ub[(size_t)(k0 + 4 + kk) * Lq];
            const float* wrow = Wt + (size_t)(k0 + kk) * Hq + o0;  // uniform
            #pragma unroll
            for (int o = 0; o < 32; ++o)
                acc[o] = fmaf(wrow[o], uv, acc[o]);
        }
    }

    #pragma unroll
    for (int o = 0; o < 32; ++o) {
        size_t idx = ((size_t)b * Hq + o0 + o) * Lq + l0 + lane;
        out[idx] = acc[o] + bias[o0 + o] + x[idx];
    }
}

// ---------------------------------------------------------------------------
extern "C" void kernel_launch(void* const* d_in, const int* in_sizes, int n_in,
                              void* d_out, int out_size, void* d_ws, size_t ws_size,
                              hipStream_t stream) {
    (void)in_sizes; (void)n_in; (void)out_size; (void)ws_size;
    const float* x          = (const float*)d_in[0];
    const float* ln_w       = (const float*)d_in[1];
    const float* ln_b       = (const float*)d_in[2];
    const float* log_dt     = (const float*)d_in[3];
    const float* log_A_real = (const float*)d_in[4];
    const float* A_imag     = (const float*)d_in[5];
    const float* B_re       = (const float*)d_in[6];
    const float* B_im       = (const float*)d_in[7];
    const float* C_re       = (const float*)d_in[8];
    const float* C_im       = (const float*)d_in[9];
    const float* Dv         = (const float*)d_in[10];
    const float* W          = (const float*)d_in[11];
    const float* b_out      = (const float*)d_in[12];
    float* out = (float*)d_out;
    float* ws  = (float*)d_ws;

    float* wr = ws;
    float* wi = ws + PARAM;
    float* a0 = ws + 2 * PARAM;
    float* b0 = ws + 3 * PARAM;
    float* a1 = ws + 4 * PARAM;
    float* b1 = ws + 5 * PARAM;
    float* Wt = ws + 6 * PARAM;                    // 512*512
    float* z  = Wt + Hq * Hq;                      // B*H*L
    float* y0 = z  + (size_t)Bq * Hq * Lq;         // holds u after scan tail
    float* y1 = y0 + (size_t)Bq * Hq * Lq;

    prep_kernel<<<PARAM / 256, 256, 0, stream>>>(log_dt, log_A_real, A_imag,
                                                 B_re, B_im, C_re, C_im,
                                                 wr, wi, a0, b0, a1, b1);
    transpose_kernel<<<dim3(Hq / 32, Hq / 32), 256, 0, stream>>>(W, Wt);
    ln_kernel<<<Bq * (Lq / 16), 256, 0, stream>>>(x, ln_w, ln_b, z);
    scan_kernel<<<Bq * Hq, 64, 0, stream>>>(z, wr, wi, a0, b0, a1, b1, Dv, y0, y1);
    gemm_kernel<<<dim3(Lq / 64, Hq / 128, Bq), 256, 0, stream>>>(y0, Wt, b_out, x, out);
}

// Round 4
// 363.792 us; speedup vs baseline: 1.7141x; 1.7141x over previous
//
#include <hip/hip_runtime.h>
#include <math.h>

#define Bq 4
#define Hq 512
#define Nq 64
#define Lq 2048
#define PARAM (Hq*Nq)   // 32768

typedef float v2f __attribute__((ext_vector_type(2)));

// ---------------------------------------------------------------------------
// Phase 1: per-(h,n) parameter prep.
// ---------------------------------------------------------------------------
__global__ void prep_kernel(const float* __restrict__ log_dt,
                            const float* __restrict__ log_A_real,
                            const float* __restrict__ A_imag,
                            const float* __restrict__ B_re, const float* __restrict__ B_im,
                            const float* __restrict__ C_re, const float* __restrict__ C_im,
                            float* __restrict__ wr_, float* __restrict__ wi_,
                            float* __restrict__ a0, float* __restrict__ b0,
                            float* __restrict__ a1, float* __restrict__ b1) {
    int idx = blockIdx.x * blockDim.x + threadIdx.x;
    if (idx >= PARAM) return;
    int h = idx >> 6;
    float dt = expf(log_dt[h]);
    float Ar = -expf(log_A_real[idx]);
    float Ai = A_imag[idx];
    float er = expf(Ar * dt);
    float wr = er * cosf(Ai * dt);
    float wi = er * sinf(Ai * dt);
    wr_[idx] = wr; wi_[idx] = wi;
    float mr = wr - 1.0f, mi = wi;
    float den = Ar * Ar + Ai * Ai;
    float qr = (mr * Ar + mi * Ai) / den;
    float qi = (mi * Ar - mr * Ai) / den;
    float Br = B_re[idx], Bi = B_im[idx];
    float dBr = Br * qr - Bi * qi;
    float dBi = Br * qi + Bi * qr;
    float cr = C_re[idx], ci = C_im[idx];
    a0[idx] =  2.0f * (cr * dBr - ci * dBi);
    b0[idx] = -2.0f * (cr * dBi + ci * dBr);
    cr = C_re[PARAM + idx]; ci = C_im[PARAM + idx];
    a1[idx] =  2.0f * (cr * dBr - ci * dBi);
    b1[idx] = -2.0f * (cr * dBi + ci * dBr);
}

// ---------------------------------------------------------------------------
// Phase 1b: Wt[k][o] = W[o][k]  (512x512) so GEMM s_loads contiguous o.
// ---------------------------------------------------------------------------
__global__ __launch_bounds__(256)
void transpose_kernel(const float* __restrict__ W, float* __restrict__ Wt) {
    __shared__ float t[32][33];
    int bx = blockIdx.x * 32;          // k base
    int by = blockIdx.y * 32;          // o base
    int tx = threadIdx.x & 31, ty = threadIdx.x >> 5;   // ty 0..7
    #pragma unroll
    for (int r = 0; r < 4; ++r)
        t[ty + 8 * r][tx] = W[(size_t)(by + ty + 8 * r) * Hq + bx + tx];
    __syncthreads();
    #pragma unroll
    for (int r = 0; r < 4; ++r)
        Wt[(size_t)(bx + ty + 8 * r) * Hq + by + tx] = t[tx][ty + 8 * r];
}

// ---------------------------------------------------------------------------
// Phase 2: LayerNorm over H per (b,l). 512 blocks, 16l x 16h.
// ---------------------------------------------------------------------------
__global__ __launch_bounds__(256)
void ln_kernel(const float* __restrict__ x, const float* __restrict__ lnw,
               const float* __restrict__ lnb, float* __restrict__ z) {
    int blk = blockIdx.x;
    int b  = blk / (Lq / 16);
    int l0 = (blk % (Lq / 16)) * 16;
    int tx = threadIdx.x & 15;   // l within tile
    int ty = threadIdx.x >> 4;   // h group
    const float* xb = x + (size_t)b * Hq * Lq;
    float s = 0.f, s2 = 0.f;
    for (int h = ty; h < Hq; h += 16) {
        float v = xb[h * Lq + l0 + tx];
        s += v; s2 += v * v;
    }
    __shared__ float rs_[16][17], r2_[16][17], mu_s[16], sg_s[16];
    rs_[ty][tx] = s; r2_[ty][tx] = s2;
    __syncthreads();
    if (ty == 0) {
        float a = 0.f, c = 0.f;
        #pragma unroll
        for (int i = 0; i < 16; ++i) { a += rs_[i][tx]; c += r2_[i][tx]; }
        float mu = a * (1.0f / Hq);
        float var = c * (1.0f / Hq) - mu * mu;
        mu_s[tx] = mu;
        sg_s[tx] = rsqrtf(var + 1e-5f);
    }
    __syncthreads();
    float mu = mu_s[tx], rs = sg_s[tx];
    float* zb = z + (size_t)b * Hq * Lq;
    for (int h = ty; h < Hq; h += 16) {
        float v = xb[h * Lq + l0 + tx];
        zb[h * Lq + l0 + tx] = (v - mu) * rs * lnw[h] + lnb[h];
    }
}

// ---------------------------------------------------------------------------
// Phase 3: fused bidirectional SSM scan + activation epilogue.
// One wave per (b,h); lane n = state index; packed fp32 carries BOTH
// directions. 16-column transpose tiles keep LDS at ~8.8 KB.
// ---------------------------------------------------------------------------
__global__ __launch_bounds__(64)
void scan_kernel(const float* __restrict__ z,
                 const float* __restrict__ wr_, const float* __restrict__ wi_,
                 const float* __restrict__ a0, const float* __restrict__ b0,
                 const float* __restrict__ a1, const float* __restrict__ b1,
                 const float* __restrict__ Dv,
                 float* __restrict__ y0, float* __restrict__ y1) {
    int bh = blockIdx.x;               // 0..B*H-1
    int h = bh & (Hq - 1);
    int n = threadIdx.x;
    int pidx = h * Nq + n;
    float wr = wr_[pidx], wi = wi_[pidx];
    v2f wr2 = { wr, wr }, wi2 = { wi, wi };
    v2f pa = { a0[pidx], a1[pidx] };
    v2f pb = { b0[pidx], b1[pidx] };

    __shared__ float tile_f[64][17];
    __shared__ float tile_b[64][17];
    __shared__ v2f zp[16];             // interleaved {z_fwd, z_bwd} per k

    const float* zz = z + (size_t)bh * Lq;
    float* y0r = y0 + (size_t)bh * Lq;
    float* y1r = y1 + (size_t)bh * Lq;

    v2f sr = {0.f, 0.f}, si = {0.f, 0.f};
    int tloc = n & 15;

    for (int q0 = 0; q0 < Lq; q0 += 16) {
        if (n < 16)                  ((float*)zp)[2 * n]            = zz[q0 + n];
        else if (n >= 32 && n < 48)  ((float*)zp)[2 * (n - 32) + 1] = zz[Lq - 1 - q0 - (n - 32)];
        __syncthreads();
        #pragma unroll
        for (int k = 0; k < 16; ++k) {
            v2f zt = zp[k];                                   // b64 broadcast
            v2f t1 = __builtin_elementwise_fma(wi2, si, -zt); // wi*si - z
            v2f t2 = wi2 * sr;
            sr = __builtin_elementwise_fma(wr2, sr, -t1);     // wr*sr-wi*si+z
            si = __builtin_elementwise_fma(wr2, si, t2);
            v2f p = __builtin_elementwise_fma(pa, sr, pb * si);
            tile_f[n][k] = p.x;
            tile_b[n][k] = p.y;
        }
        __syncthreads();
        int quad = n >> 4;
        float af = 0.f, ab = 0.f;
        #pragma unroll
        for (int j = 0; j < 16; ++j) {
            af += tile_f[quad * 16 + j][tloc];
            ab += tile_b[quad * 16 + j][tloc];
        }
        af += __shfl_xor(af, 16, 64);
        af += __shfl_xor(af, 32, 64);
        ab += __shfl_xor(ab, 16, 64);
        ab += __shfl_xor(ab, 32, 64);
        if (n < 16) {
            y0r[q0 + n] = af;
        } else if (n < 32) {
            int pos = Lq - 2 - q0 - tloc;
            if (pos >= 0) y1r[pos] = ab;     // y1[L-1] handled as 0 in tail
        }
    }
    __syncthreads();
    // ---- activation tail: u = gelu(y0 + y1 + D*z), in-place into y0 ----
    float d = Dv[h];
    for (int t = n; t < Lq; t += 64) {
        float v0 = y0r[t];
        float v1 = (t == Lq - 1) ? 0.f : y1r[t];
        float v = v0 + v1 + d * zz[t];
        float g = 0.7978845608028654f * (v + 0.044715f * v * v * v);
        g = fminf(fmaxf(g, -15.f), 15.f);
        float e = __expf(2.0f * g);
        float th = (e - 1.0f) * __builtin_amdgcn_rcpf(e + 1.0f);
        y0r[t] = 0.5f * v * (1.0f + th);
    }
}

// ---------------------------------------------------------------------------
// Phase 5: out[b,o,l] = bias[o] + x[b,o,l] + sum_k W[o,k]*u[b,k,l]
// Scalar-broadcast GEMM, zero LDS. CRITICAL: o0 derives from blockIdx ONLY,
// so Wt row addresses are per-thread provably uniform -> s_load_dwordx16 on
// the scalar pipe (round-3 failure: threadIdx-derived o0 never scalarizes).
// 16 o per block, waves split l. Per k per wave: 1 coalesced u load +
// 16 v_fmac(s_w, v_u). Grid (8, 32, 4) = 1024 blocks = 16 waves/CU.
// ---------------------------------------------------------------------------
__global__ __launch_bounds__(256)
void gemm_kernel(const float* __restrict__ u, const float* __restrict__ Wt,
                 const float* __restrict__ bias, const float* __restrict__ x,
                 float* __restrict__ out) {
    int o0 = blockIdx.y * 16;                    // block-uniform (blockIdx only!)
    int b  = blockIdx.z;
    int l  = blockIdx.x * 256 + threadIdx.x;
    const float* ub = u + (size_t)b * Hq * Lq + l;

    float acc[16];
    #pragma unroll
    for (int o = 0; o < 16; ++o) acc[o] = 0.f;

    // 8-deep u prefetch ring; tail overrun (rows 512..519) lands in the
    // allocated y1 region — value unused.
    float up[8];
    #pragma unroll
    for (int i = 0; i < 8; ++i) up[i] = ub[(size_t)i * Lq];

    for (int k0 = 0; k0 < Hq; k0 += 8) {
        #pragma unroll
        for (int kk = 0; kk < 8; ++kk) {
            float uv = up[kk];
            up[kk] = ub[(size_t)(k0 + 8 + kk) * Lq];
            const float* wrow = Wt + (size_t)(k0 + kk) * Hq + o0;  // uniform
            #pragma unroll
            for (int o = 0; o < 16; ++o)
                acc[o] = fmaf(wrow[o], uv, acc[o]);
        }
    }

    #pragma unroll
    for (int o = 0; o < 16; ++o) {
        size_t idx = ((size_t)b * Hq + o0 + o) * Lq + l;
        out[idx] = acc[o] + bias[o0 + o] + x[idx];
    }
}

// ---------------------------------------------------------------------------
extern "C" void kernel_launch(void* const* d_in, const int* in_sizes, int n_in,
                              void* d_out, int out_size, void* d_ws, size_t ws_size,
                              hipStream_t stream) {
    (void)in_sizes; (void)n_in; (void)out_size; (void)ws_size;
    const float* x          = (const float*)d_in[0];
    const float* ln_w       = (const float*)d_in[1];
    const float* ln_b       = (const float*)d_in[2];
    const float* log_dt     = (const float*)d_in[3];
    const float* log_A_real = (const float*)d_in[4];
    const float* A_imag     = (const float*)d_in[5];
    const float* B_re       = (const float*)d_in[6];
    const float* B_im       = (const float*)d_in[7];
    const float* C_re       = (const float*)d_in[8];
    const float* C_im       = (const float*)d_in[9];
    const float* Dv         = (const float*)d_in[10];
    const float* W          = (const float*)d_in[11];
    const float* b_out      = (const float*)d_in[12];
    float* out = (float*)d_out;
    float* ws  = (float*)d_ws;

    float* wr = ws;
    float* wi = ws + PARAM;
    float* a0 = ws + 2 * PARAM;
    float* b0 = ws + 3 * PARAM;
    float* a1 = ws + 4 * PARAM;
    float* b1 = ws + 5 * PARAM;
    float* Wt = ws + 6 * PARAM;                    // 512*512
    float* z  = Wt + Hq * Hq;                      // B*H*L
    float* y0 = z  + (size_t)Bq * Hq * Lq;         // holds u after scan tail
    float* y1 = y0 + (size_t)Bq * Hq * Lq;

    prep_kernel<<<PARAM / 256, 256, 0, stream>>>(log_dt, log_A_real, A_imag,
                                                 B_re, B_im, C_re, C_im,
                                                 wr, wi, a0, b0, a1, b1);
    transpose_kernel<<<dim3(Hq / 32, Hq / 32), 256, 0, stream>>>(W, Wt);
    ln_kernel<<<Bq * (Lq / 16), 256, 0, stream>>>(x, ln_w, ln_b, z);
    scan_kernel<<<Bq * Hq, 64, 0, stream>>>(z, wr, wi, a0, b0, a1, b1, Dv, y0, y1);
    gemm_kernel<<<dim3(Lq / 256, Hq / 16, Bq), 256, 0, stream>>>(y0, Wt, b_out, x, out);
}